// Round 1
// baseline (482.991 us; speedup 1.0000x reference)
//
#include <hip/hip_runtime.h>

#define LOG2E 1.4426950408889634f
#define LN2   0.6931471805599453f

// ---------------------------------------------------------------------------
// Kernel A: xw = leaky_relu(x @ W + b)   x:[M,256] W:[256,64] b:[64] -> [M,64]
// block = 256 threads = 4 waves; each wave computes 16 rows, lane = out col.
// x values are wave-uniform -> scalar s_load; W loads coalesced (256B/inst).
// grid = (ceil(M/64), 2)  (y = encoder select)
// ---------------------------------------------------------------------------
__global__ __launch_bounds__(256) void enc_kernel(
    const float* __restrict__ x0, const float* __restrict__ W0, const float* __restrict__ b0,
    const float* __restrict__ x1, const float* __restrict__ W1, const float* __restrict__ b1,
    float* __restrict__ out, int M)
{
  const int enc = blockIdx.y;
  const float* __restrict__ x = enc ? x1 : x0;
  const float* __restrict__ W = enc ? W1 : W0;
  const float* __restrict__ b = enc ? b1 : b0;
  float* __restrict__ o = out + (size_t)enc * (size_t)M * 64u;

  const int lane = threadIdx.x & 63;
  const int wid  = threadIdx.x >> 6;
  int row0 = __builtin_amdgcn_readfirstlane(blockIdx.x * 64 + wid * 16);
  const float* __restrict__ xrow = x + (size_t)row0 * 256u;

  float acc[16];
#pragma unroll
  for (int r = 0; r < 16; ++r) acc[r] = 0.f;

  if (row0 + 16 <= M) {
#pragma unroll 4
    for (int k = 0; k < 256; ++k) {
      float wv = W[k * 64 + lane];
#pragma unroll
      for (int r = 0; r < 16; ++r)
        acc[r] = fmaf(xrow[r * 256 + k], wv, acc[r]);
    }
    float bias = b[lane];
#pragma unroll
    for (int r = 0; r < 16; ++r) {
      float v = acc[r] + bias;
      v = fmaxf(v, 0.01f * v);                       // leaky relu (slope<1)
      o[(size_t)(row0 + r) * 64u + lane] = v;
    }
  } else if (row0 < M) {
    int nr = M - row0;                               // 1..15 (tail block only)
    for (int k = 0; k < 256; ++k) {
      float wv = W[k * 64 + lane];
      for (int r = 0; r < nr; ++r)
        acc[r] = fmaf(xrow[r * 256 + k], wv, acc[r]);
    }
    float bias = b[lane];
    for (int r = 0; r < nr; ++r) {
      float v = acc[r] + bias;
      v = fmaxf(v, 0.01f * v);
      o[(size_t)(row0 + r) * 64u + lane] = v;
    }
  }
}

// ---------------------------------------------------------------------------
// Kernel B: pw = xw @ W_edge[0:64,:]  ;  pi = xi @ W_edge[64:128,:]
// thread = one row; output rows padded to 12 floats (3x float4, 16B aligned).
// grid = (ceil(M/256), 2)  (y = encoder select; keeps W2 addr wave-uniform)
// ---------------------------------------------------------------------------
__global__ __launch_bounds__(256) void proj_kernel(
    const float* __restrict__ feats, const float* __restrict__ W_edge,
    float* __restrict__ ws, int M)
{
  const int enc = blockIdx.y;
  int row = blockIdx.x * 256 + threadIdx.x;
  if (row >= M) return;
  const float4* __restrict__ f4 =
      (const float4*)(feats + ((size_t)enc * M + row) * 64u);
  const float* __restrict__ W2 = W_edge + enc * 640;   // 64 rows x 10 cols

  float acc[10];
#pragma unroll
  for (int k = 0; k < 10; ++k) acc[k] = 0.f;

#pragma unroll 4
  for (int n4 = 0; n4 < 16; ++n4) {
    float4 xv = f4[n4];
    const float* w = W2 + n4 * 40;
#pragma unroll
    for (int k = 0; k < 10; ++k) acc[k] = fmaf(xv.x, w[k],      acc[k]);
#pragma unroll
    for (int k = 0; k < 10; ++k) acc[k] = fmaf(xv.y, w[10 + k], acc[k]);
#pragma unroll
    for (int k = 0; k < 10; ++k) acc[k] = fmaf(xv.z, w[20 + k], acc[k]);
#pragma unroll
    for (int k = 0; k < 10; ++k) acc[k] = fmaf(xv.w, w[30 + k], acc[k]);
  }

  float* orow = ws + ((size_t)enc * M + row) * 12u;
#pragma unroll
  for (int k = 0; k < 10; ++k) orow[k] = acc[k];
  orow[10] = 0.f; orow[11] = 0.f;
}

// ---------------------------------------------------------------------------
// Kernel C: logits[e] = pw[e0] + pi[e1] + b_edge ; out = log_softmax(logits)
// thread = one edge; gathers are 3x float4 (48B) per endpoint from the small
// L2/L3-resident pw/pi tables; writes staged through LDS for coalescing.
// ---------------------------------------------------------------------------
__global__ __launch_bounds__(256) void edge_kernel(
    const int* __restrict__ ei, const float* __restrict__ ws,
    const float* __restrict__ b_edge, float* __restrict__ out,
    int E, int M)
{
  __shared__ float sm[256 * 11];
  long e = (long)blockIdx.x * 256 + threadIdx.x;
  float l[10];
#pragma unroll
  for (int k = 0; k < 10; ++k) l[k] = 0.f;

  if (e < E) {
    int e0 = ei[e];
    int e1 = ei[E + e];
    const float4* pw = (const float4*)ws + (size_t)e0 * 3u;
    const float4* pi = (const float4*)ws + ((size_t)M + e1) * 3u;
    float4 a0 = pw[0], a1 = pw[1], a2 = pw[2];
    float4 c0 = pi[0], c1 = pi[1], c2 = pi[2];
    l[0] = a0.x + c0.x + b_edge[0];
    l[1] = a0.y + c0.y + b_edge[1];
    l[2] = a0.z + c0.z + b_edge[2];
    l[3] = a0.w + c0.w + b_edge[3];
    l[4] = a1.x + c1.x + b_edge[4];
    l[5] = a1.y + c1.y + b_edge[5];
    l[6] = a1.z + c1.z + b_edge[6];
    l[7] = a1.w + c1.w + b_edge[7];
    l[8] = a2.x + c2.x + b_edge[8];
    l[9] = a2.y + c2.y + b_edge[9];
    float m = l[0];
#pragma unroll
    for (int k = 1; k < 10; ++k) m = fmaxf(m, l[k]);
    float s = 0.f;
#pragma unroll
    for (int k = 0; k < 10; ++k) { l[k] = (l[k] - m) * LOG2E; s += exp2f(l[k]); }
    float ls = log2f(s);
#pragma unroll
    for (int k = 0; k < 10; ++k) l[k] = (l[k] - ls) * LN2;
  }

#pragma unroll
  for (int k = 0; k < 10; ++k) sm[threadIdx.x * 11 + k] = l[k];
  __syncthreads();
  long obase = (long)blockIdx.x * 2560;
  long lim = (long)E * 10;
#pragma unroll
  for (int j = 0; j < 10; ++j) {
    int jj = j * 256 + threadIdx.x;
    long oi = obase + jj;
    if (oi < lim) out[oi] = sm[(jj / 10) * 11 + (jj % 10)];
  }
}

// ---------------------------------------------------------------------------
// Fallback (only if d_ws too small): per-edge full 128-dot from features.
// ---------------------------------------------------------------------------
__global__ __launch_bounds__(256) void edge_kernel_direct(
    const int* __restrict__ ei, const float* __restrict__ feats,
    const float* __restrict__ W_edge, const float* __restrict__ b_edge,
    float* __restrict__ out, int E, int M)
{
  __shared__ float sm[256 * 11];
  long e = (long)blockIdx.x * 256 + threadIdx.x;
  float l[10];
#pragma unroll
  for (int k = 0; k < 10; ++k) l[k] = 0.f;

  if (e < E) {
    int e0 = ei[e];
    int e1 = ei[E + e];
#pragma unroll
    for (int k = 0; k < 10; ++k) l[k] = b_edge[k];
    const float4* fw = (const float4*)(feats + (size_t)e0 * 64u);
    const float4* fi = (const float4*)(feats + ((size_t)M + e1) * 64u);
#pragma unroll 4
    for (int n4 = 0; n4 < 16; ++n4) {
      float4 xv = fw[n4];
      const float* w = W_edge + n4 * 40;
#pragma unroll
      for (int k = 0; k < 10; ++k) l[k] = fmaf(xv.x, w[k],      l[k]);
#pragma unroll
      for (int k = 0; k < 10; ++k) l[k] = fmaf(xv.y, w[10 + k], l[k]);
#pragma unroll
      for (int k = 0; k < 10; ++k) l[k] = fmaf(xv.z, w[20 + k], l[k]);
#pragma unroll
      for (int k = 0; k < 10; ++k) l[k] = fmaf(xv.w, w[30 + k], l[k]);
    }
#pragma unroll 4
    for (int n4 = 0; n4 < 16; ++n4) {
      float4 xv = fi[n4];
      const float* w = W_edge + 640 + n4 * 40;
#pragma unroll
      for (int k = 0; k < 10; ++k) l[k] = fmaf(xv.x, w[k],      l[k]);
#pragma unroll
      for (int k = 0; k < 10; ++k) l[k] = fmaf(xv.y, w[10 + k], l[k]);
#pragma unroll
      for (int k = 0; k < 10; ++k) l[k] = fmaf(xv.z, w[20 + k], l[k]);
#pragma unroll
      for (int k = 0; k < 10; ++k) l[k] = fmaf(xv.w, w[30 + k], l[k]);
    }
    float m = l[0];
#pragma unroll
    for (int k = 1; k < 10; ++k) m = fmaxf(m, l[k]);
    float s = 0.f;
#pragma unroll
    for (int k = 0; k < 10; ++k) { l[k] = (l[k] - m) * LOG2E; s += exp2f(l[k]); }
    float ls = log2f(s);
#pragma unroll
    for (int k = 0; k < 10; ++k) l[k] = (l[k] - ls) * LN2;
  }

#pragma unroll
  for (int k = 0; k < 10; ++k) sm[threadIdx.x * 11 + k] = l[k];
  __syncthreads();
  long obase = (long)blockIdx.x * 2560;
  long lim = (long)E * 10;
#pragma unroll
  for (int j = 0; j < 10; ++j) {
    int jj = j * 256 + threadIdx.x;
    long oi = obase + jj;
    if (oi < lim) out[oi] = sm[(jj / 10) * 11 + (jj % 10)];
  }
}

extern "C" void kernel_launch(void* const* d_in, const int* in_sizes, int n_in,
                              void* d_out, int out_size, void* d_ws, size_t ws_size,
                              hipStream_t stream)
{
  const float* x_w = (const float*)d_in[0];
  const float* x_i = (const float*)d_in[1];
  const int*   ei  = (const int*)d_in[2];
  const float* W_w = (const float*)d_in[3];
  const float* b_w = (const float*)d_in[4];
  const float* W_i = (const float*)d_in[5];
  const float* b_i = (const float*)d_in[6];
  const float* W_e = (const float*)d_in[7];
  const float* b_e = (const float*)d_in[8];
  float* out = (float*)d_out;

  const int M = in_sizes[0] / 256;   // 100000
  const int E = in_sizes[2] / 2;     // 2000000

  dim3 gA((M + 63) / 64, 2);
  enc_kernel<<<gA, 256, 0, stream>>>(x_w, W_w, b_w, x_i, W_i, b_i, out, M);

  float* logout = out + (size_t)2 * (size_t)M * 64u;
  size_t ws_need = (size_t)2 * (size_t)M * 12u * sizeof(float);

  if (ws_size >= ws_need) {
    float* ws = (float*)d_ws;
    dim3 gB((M + 255) / 256, 2);
    proj_kernel<<<gB, 256, 0, stream>>>(out, W_e, ws, M);
    dim3 gC((unsigned)((E + 255) / 256));
    edge_kernel<<<gC, 256, 0, stream>>>(ei, ws, b_e, logout, E, M);
  } else {
    dim3 gC((unsigned)((E + 255) / 256));
    edge_kernel_direct<<<gC, 256, 0, stream>>>(ei, out, W_e, b_e, logout, E, M);
  }
}

// Round 2
// 156.431 us; speedup vs baseline: 3.0876x; 3.0876x over previous
//
#include <hip/hip_runtime.h>
#include <hip/hip_bf16.h>

#define LOG2E 1.4426950408889634f
#define LN2   0.6931471805599453f

typedef __attribute__((ext_vector_type(8))) short bf16x8;
typedef __attribute__((ext_vector_type(4))) float f32x4;

static __device__ __forceinline__ short f2bf(float f) {
  __hip_bfloat16 h = __float2bfloat16(f);
  return *reinterpret_cast<short*>(&h);
}

// ---------------------------------------------------------------------------
// wprep: pack W_worker/W_item (f32 [256][64]) into per-lane MFMA B-fragments.
// Layout: wfrag[enc][f][lane][j], f = nsub*8 + ks, 8 bf16 (16B) per entry.
// Element (f,lane,j) = W[k][n], n = nsub*16 + (lane&15), k = ks*32+(lane>>4)*8+j.
// 2*32*64*16B = 64 KB total. grid 16x256.
// ---------------------------------------------------------------------------
__global__ __launch_bounds__(256) void wprep_kernel(
    const float* __restrict__ Ww, const float* __restrict__ Wi,
    ushort* __restrict__ wfrag)
{
  int id = blockIdx.x * 256 + threadIdx.x;       // 0..4095
  if (id >= 4096) return;
  int enc  = id >> 11;
  int f    = (id >> 6) & 31;
  int l    = id & 63;
  int nsub = f >> 3, ks = f & 7;
  const float* __restrict__ W = enc ? Wi : Ww;
  int n  = nsub * 16 + (l & 15);
  int k0 = ks * 32 + (l >> 4) * 8;
  ushort* dst = wfrag + ((size_t)(enc * 32 + f) * 64 + l) * 8;
#pragma unroll
  for (int j = 0; j < 8; ++j)
    dst[j] = (ushort)f2bf(W[(size_t)(k0 + j) * 64 + n]);
}

// ---------------------------------------------------------------------------
// enc_mfma: xw = leaky_relu(x @ W + b) via bf16 MFMA 16x16x32, f32 accum.
// Block = 4 waves; each wave owns one 16-row strip (16x256 @ 256x64 -> 16x64).
// W fragments held in VGPRs (loaded coalesced from wfrag, L2-hot);
// x streamed from HBM as 16 independent dwordx4 loads per wave (fully
// unrolled -> deep in-flight queue), converted to bf16 in-register.
// ---------------------------------------------------------------------------
__global__ __launch_bounds__(256) void enc_mfma_kernel(
    const float* __restrict__ x0, const float* __restrict__ b0,
    const float* __restrict__ x1, const float* __restrict__ b1,
    const ushort* __restrict__ wfrag, float* __restrict__ out, int M)
{
  const int enc = blockIdx.y;
  const float* __restrict__ x   = enc ? x1 : x0;
  const float* __restrict__ bia = enc ? b1 : b0;
  float* __restrict__ o = out + (size_t)enc * (size_t)M * 64u;

  const int lane = threadIdx.x & 63;
  const int wid  = threadIdx.x >> 6;
  const int nstrips = (M + 15) >> 4;
  int strip = blockIdx.x * 4 + wid;
  if (strip >= nstrips) return;
  const int row0 = strip * 16;

  // --- W fragments: 32 x bf16x8 = 128 VGPRs, coalesced 16B/lane loads ---
  bf16x8 bf[4][8];
  const bf16x8* wp = (const bf16x8*)wfrag + (size_t)enc * 32 * 64 + lane;
#pragma unroll
  for (int nsub = 0; nsub < 4; ++nsub)
#pragma unroll
    for (int ks = 0; ks < 8; ++ks)
      bf[nsub][ks] = wp[(size_t)(nsub * 8 + ks) * 64];

  // --- x strip: lane reads row row0+(lane&15), k-chunk (lane>>4)*8 .. +8 ---
  int rowL = row0 + (lane & 15);
  if (rowL >= M) rowL = M - 1;                    // clamp (tail safety)
  const float* __restrict__ xr = x + (size_t)rowL * 256u + (lane >> 4) * 8;
  f32x4 xa[8], xb[8];
#pragma unroll
  for (int ks = 0; ks < 8; ++ks) {
    xa[ks] = *(const f32x4*)(xr + ks * 32);
    xb[ks] = *(const f32x4*)(xr + ks * 32 + 4);
  }

  f32x4 acc[4];
#pragma unroll
  for (int nsub = 0; nsub < 4; ++nsub) acc[nsub] = f32x4{0.f, 0.f, 0.f, 0.f};

#pragma unroll
  for (int ks = 0; ks < 8; ++ks) {
    bf16x8 a;
    a[0] = f2bf(xa[ks].x); a[1] = f2bf(xa[ks].y);
    a[2] = f2bf(xa[ks].z); a[3] = f2bf(xa[ks].w);
    a[4] = f2bf(xb[ks].x); a[5] = f2bf(xb[ks].y);
    a[6] = f2bf(xb[ks].z); a[7] = f2bf(xb[ks].w);
#pragma unroll
    for (int nsub = 0; nsub < 4; ++nsub)
      acc[nsub] = __builtin_amdgcn_mfma_f32_16x16x32_bf16(
          a, bf[nsub][ks], acc[nsub], 0, 0, 0);
  }

  // --- epilogue: bias + leaky relu, C/D layout col=lane&15, row=(lane>>4)*4+r
  const int crow = row0 + (lane >> 4) * 4;
  const int ncol = lane & 15;
#pragma unroll
  for (int nsub = 0; nsub < 4; ++nsub) {
    float bv = bia[nsub * 16 + ncol];
#pragma unroll
    for (int r = 0; r < 4; ++r) {
      int rr = crow + r;
      if (rr < M) {
        float v = acc[nsub][r] + bv;
        v = fmaxf(v, 0.01f * v);
        o[(size_t)rr * 64u + nsub * 16 + ncol] = v;
      }
    }
  }
}

// ---------------------------------------------------------------------------
// Kernel B: pw = xw @ W_edge[0:64,:]  ;  pi = xi @ W_edge[64:128,:]
// thread = one row; output rows padded to 12 floats (3x float4, 16B aligned).
// ---------------------------------------------------------------------------
__global__ __launch_bounds__(256) void proj_kernel(
    const float* __restrict__ feats, const float* __restrict__ W_edge,
    float* __restrict__ ws, int M)
{
  const int enc = blockIdx.y;
  int row = blockIdx.x * 256 + threadIdx.x;
  if (row >= M) return;
  const float4* __restrict__ f4 =
      (const float4*)(feats + ((size_t)enc * M + row) * 64u);
  const float* __restrict__ W2 = W_edge + enc * 640;   // 64 rows x 10 cols

  float acc[10];
#pragma unroll
  for (int k = 0; k < 10; ++k) acc[k] = 0.f;

#pragma unroll 4
  for (int n4 = 0; n4 < 16; ++n4) {
    float4 xv = f4[n4];
    const float* w = W2 + n4 * 40;
#pragma unroll
    for (int k = 0; k < 10; ++k) acc[k] = fmaf(xv.x, w[k],      acc[k]);
#pragma unroll
    for (int k = 0; k < 10; ++k) acc[k] = fmaf(xv.y, w[10 + k], acc[k]);
#pragma unroll
    for (int k = 0; k < 10; ++k) acc[k] = fmaf(xv.z, w[20 + k], acc[k]);
#pragma unroll
    for (int k = 0; k < 10; ++k) acc[k] = fmaf(xv.w, w[30 + k], acc[k]);
  }

  float* orow = ws + ((size_t)enc * M + row) * 12u;
#pragma unroll
  for (int k = 0; k < 10; ++k) orow[k] = acc[k];
  orow[10] = 0.f; orow[11] = 0.f;
}

// ---------------------------------------------------------------------------
// Kernel C: logits[e] = pw[e0] + pi[e1] + b_edge ; out = log_softmax(logits)
// ---------------------------------------------------------------------------
__global__ __launch_bounds__(256) void edge_kernel(
    const int* __restrict__ ei, const float* __restrict__ ws,
    const float* __restrict__ b_edge, float* __restrict__ out,
    int E, int M)
{
  __shared__ float sm[256 * 11];
  long e = (long)blockIdx.x * 256 + threadIdx.x;
  float l[10];
#pragma unroll
  for (int k = 0; k < 10; ++k) l[k] = 0.f;

  if (e < E) {
    int e0 = ei[e];
    int e1 = ei[E + e];
    const float4* pw = (const float4*)ws + (size_t)e0 * 3u;
    const float4* pi = (const float4*)ws + ((size_t)M + e1) * 3u;
    float4 a0 = pw[0], a1 = pw[1], a2 = pw[2];
    float4 c0 = pi[0], c1 = pi[1], c2 = pi[2];
    l[0] = a0.x + c0.x + b_edge[0];
    l[1] = a0.y + c0.y + b_edge[1];
    l[2] = a0.z + c0.z + b_edge[2];
    l[3] = a0.w + c0.w + b_edge[3];
    l[4] = a1.x + c1.x + b_edge[4];
    l[5] = a1.y + c1.y + b_edge[5];
    l[6] = a1.z + c1.z + b_edge[6];
    l[7] = a1.w + c1.w + b_edge[7];
    l[8] = a2.x + c2.x + b_edge[8];
    l[9] = a2.y + c2.y + b_edge[9];
    float m = l[0];
#pragma unroll
    for (int k = 1; k < 10; ++k) m = fmaxf(m, l[k]);
    float s = 0.f;
#pragma unroll
    for (int k = 0; k < 10; ++k) { l[k] = (l[k] - m) * LOG2E; s += exp2f(l[k]); }
    float ls = log2f(s);
#pragma unroll
    for (int k = 0; k < 10; ++k) l[k] = (l[k] - ls) * LN2;
  }

#pragma unroll
  for (int k = 0; k < 10; ++k) sm[threadIdx.x * 11 + k] = l[k];
  __syncthreads();
  long obase = (long)blockIdx.x * 2560;
  long lim = (long)E * 10;
#pragma unroll
  for (int j = 0; j < 10; ++j) {
    int jj = j * 256 + threadIdx.x;
    long oi = obase + jj;
    if (oi < lim) out[oi] = sm[(jj / 10) * 11 + (jj % 10)];
  }
}

// ---------------------------------------------------------------------------
// Fallback f32 encoder (only if d_ws too small for the fast path).
// ---------------------------------------------------------------------------
__global__ __launch_bounds__(256) void enc_kernel_f32(
    const float* __restrict__ x0, const float* __restrict__ W0, const float* __restrict__ b0,
    const float* __restrict__ x1, const float* __restrict__ W1, const float* __restrict__ b1,
    float* __restrict__ out, int M)
{
  const int enc = blockIdx.y;
  const float* __restrict__ x = enc ? x1 : x0;
  const float* __restrict__ W = enc ? W1 : W0;
  const float* __restrict__ b = enc ? b1 : b0;
  float* __restrict__ o = out + (size_t)enc * (size_t)M * 64u;

  const int lane = threadIdx.x & 63;
  const int wid  = threadIdx.x >> 6;
  int row0 = __builtin_amdgcn_readfirstlane(blockIdx.x * 64 + wid * 16);
  const float* __restrict__ xrow = x + (size_t)row0 * 256u;

  float acc[16];
#pragma unroll
  for (int r = 0; r < 16; ++r) acc[r] = 0.f;

  if (row0 + 16 <= M) {
#pragma unroll 4
    for (int k = 0; k < 256; ++k) {
      float wv = W[k * 64 + lane];
#pragma unroll
      for (int r = 0; r < 16; ++r)
        acc[r] = fmaf(xrow[r * 256 + k], wv, acc[r]);
    }
    float bias = b[lane];
#pragma unroll
    for (int r = 0; r < 16; ++r) {
      float v = acc[r] + bias;
      v = fmaxf(v, 0.01f * v);
      o[(size_t)(row0 + r) * 64u + lane] = v;
    }
  } else if (row0 < M) {
    int nr = M - row0;
    for (int k = 0; k < 256; ++k) {
      float wv = W[k * 64 + lane];
      for (int r = 0; r < nr; ++r)
        acc[r] = fmaf(xrow[r * 256 + k], wv, acc[r]);
    }
    float bias = b[lane];
    for (int r = 0; r < nr; ++r) {
      float v = acc[r] + bias;
      v = fmaxf(v, 0.01f * v);
      o[(size_t)(row0 + r) * 64u + lane] = v;
    }
  }
}

__global__ __launch_bounds__(256) void edge_kernel_direct(
    const int* __restrict__ ei, const float* __restrict__ feats,
    const float* __restrict__ W_edge, const float* __restrict__ b_edge,
    float* __restrict__ out, int E, int M)
{
  __shared__ float sm[256 * 11];
  long e = (long)blockIdx.x * 256 + threadIdx.x;
  float l[10];
#pragma unroll
  for (int k = 0; k < 10; ++k) l[k] = 0.f;

  if (e < E) {
    int e0 = ei[e];
    int e1 = ei[E + e];
#pragma unroll
    for (int k = 0; k < 10; ++k) l[k] = b_edge[k];
    const float4* fw = (const float4*)(feats + (size_t)e0 * 64u);
    const float4* fi = (const float4*)(feats + ((size_t)M + e1) * 64u);
#pragma unroll 4
    for (int n4 = 0; n4 < 16; ++n4) {
      float4 xv = fw[n4];
      const float* w = W_edge + n4 * 40;
#pragma unroll
      for (int k = 0; k < 10; ++k) l[k] = fmaf(xv.x, w[k],      l[k]);
#pragma unroll
      for (int k = 0; k < 10; ++k) l[k] = fmaf(xv.y, w[10 + k], l[k]);
#pragma unroll
      for (int k = 0; k < 10; ++k) l[k] = fmaf(xv.z, w[20 + k], l[k]);
#pragma unroll
      for (int k = 0; k < 10; ++k) l[k] = fmaf(xv.w, w[30 + k], l[k]);
    }
#pragma unroll 4
    for (int n4 = 0; n4 < 16; ++n4) {
      float4 xv = fi[n4];
      const float* w = W_edge + 640 + n4 * 40;
#pragma unroll
      for (int k = 0; k < 10; ++k) l[k] = fmaf(xv.x, w[k],      l[k]);
#pragma unroll
      for (int k = 0; k < 10; ++k) l[k] = fmaf(xv.y, w[10 + k], l[k]);
#pragma unroll
      for (int k = 0; k < 10; ++k) l[k] = fmaf(xv.z, w[20 + k], l[k]);
#pragma unroll
      for (int k = 0; k < 10; ++k) l[k] = fmaf(xv.w, w[30 + k], l[k]);
    }
    float m = l[0];
#pragma unroll
    for (int k = 1; k < 10; ++k) m = fmaxf(m, l[k]);
    float s = 0.f;
#pragma unroll
    for (int k = 0; k < 10; ++k) { l[k] = (l[k] - m) * LOG2E; s += exp2f(l[k]); }
    float ls = log2f(s);
#pragma unroll
    for (int k = 0; k < 10; ++k) l[k] = (l[k] - ls) * LN2;
  }

#pragma unroll
  for (int k = 0; k < 10; ++k) sm[threadIdx.x * 11 + k] = l[k];
  __syncthreads();
  long obase = (long)blockIdx.x * 2560;
  long lim = (long)E * 10;
#pragma unroll
  for (int j = 0; j < 10; ++j) {
    int jj = j * 256 + threadIdx.x;
    long oi = obase + jj;
    if (oi < lim) out[oi] = sm[(jj / 10) * 11 + (jj % 10)];
  }
}

extern "C" void kernel_launch(void* const* d_in, const int* in_sizes, int n_in,
                              void* d_out, int out_size, void* d_ws, size_t ws_size,
                              hipStream_t stream)
{
  const float* x_w = (const float*)d_in[0];
  const float* x_i = (const float*)d_in[1];
  const int*   ei  = (const int*)d_in[2];
  const float* W_w = (const float*)d_in[3];
  const float* b_w = (const float*)d_in[4];
  const float* W_i = (const float*)d_in[5];
  const float* b_i = (const float*)d_in[6];
  const float* W_e = (const float*)d_in[7];
  const float* b_e = (const float*)d_in[8];
  float* out = (float*)d_out;

  const int M = in_sizes[0] / 256;   // 100000
  const int E = in_sizes[2] / 2;     // 2000000

  float* logout = out + (size_t)2 * (size_t)M * 64u;

  const size_t pw_bytes = (size_t)2 * (size_t)M * 12u * sizeof(float);
  const size_t ws_need  = pw_bytes + 65536;     // + wfrag table

  if (ws_size >= ws_need) {
    float*  ws    = (float*)d_ws;
    ushort* wfrag = (ushort*)((char*)d_ws + pw_bytes);

    wprep_kernel<<<16, 256, 0, stream>>>(W_w, W_i, wfrag);

    const int nstrips = (M + 15) >> 4;
    dim3 gA((nstrips + 3) / 4, 2);
    enc_mfma_kernel<<<gA, 256, 0, stream>>>(x_w, b_w, x_i, b_i, wfrag, out, M);

    dim3 gB((M + 255) / 256, 2);
    proj_kernel<<<gB, 256, 0, stream>>>(out, W_e, ws, M);

    dim3 gC((unsigned)((E + 255) / 256));
    edge_kernel<<<gC, 256, 0, stream>>>(ei, ws, b_e, logout, E, M);
  } else {
    dim3 gA0((M + 63) / 64, 2);
    enc_kernel_f32<<<gA0, 256, 0, stream>>>(x_w, W_w, b_w, x_i, W_i, b_i, out, M);
    dim3 gC((unsigned)((E + 255) / 256));
    edge_kernel_direct<<<gC, 256, 0, stream>>>(ei, out, W_e, b_e, logout, E, M);
  }
}

// Round 3
// 156.063 us; speedup vs baseline: 3.0949x; 1.0024x over previous
//
#include <hip/hip_runtime.h>
#include <hip/hip_bf16.h>

#define LOG2E 1.4426950408889634f
#define LN2   0.6931471805599453f

typedef __attribute__((ext_vector_type(8))) short bf16x8;
typedef __attribute__((ext_vector_type(4))) float f32x4;

static __device__ __forceinline__ short f2bf(float f) {
  __hip_bfloat16 h = __float2bfloat16(f);
  return *reinterpret_cast<short*>(&h);
}

// ---------------------------------------------------------------------------
// wprep: pack W_worker/W_item (f32 [256][64]) into per-lane MFMA B-fragments.
// Layout: wfrag[enc][f][lane][j], f = nsub*8 + ks, 8 bf16 (16B) per entry.
// Element (f,lane,j) = W[k][n], n = nsub*16 + (lane&15), k = ks*32+(lane>>4)*8+j.
// 2*32*64*16B = 64 KB total. grid 16x256.
// ---------------------------------------------------------------------------
__global__ __launch_bounds__(256) void wprep_kernel(
    const float* __restrict__ Ww, const float* __restrict__ Wi,
    ushort* __restrict__ wfrag)
{
  int id = blockIdx.x * 256 + threadIdx.x;       // 0..4095
  if (id >= 4096) return;
  int enc  = id >> 11;
  int f    = (id >> 6) & 31;
  int l    = id & 63;
  int nsub = f >> 3, ks = f & 7;
  const float* __restrict__ W = enc ? Wi : Ww;
  int n  = nsub * 16 + (l & 15);
  int k0 = ks * 32 + (l >> 4) * 8;
  ushort* dst = wfrag + ((size_t)(enc * 32 + f) * 64 + l) * 8;
#pragma unroll
  for (int j = 0; j < 8; ++j)
    dst[j] = (ushort)f2bf(W[(size_t)(k0 + j) * 64 + n]);
}

// ---------------------------------------------------------------------------
// enc_mfma2: xw = leaky_relu(x @ W + b) via bf16 MFMA 16x16x32, f32 accum.
// W fragments staged in LDS (32KB/block, ds_read_b128 per use — compiler
// can't serialize this the way it did VGPR-resident fragments).
// Grid-stride strip loop (~6 strips/wave) with software pipeline: convert
// strip s, issue strip s+1's 16 dwordx4 loads (16KB in flight), then MFMA.
// ---------------------------------------------------------------------------
__global__ __launch_bounds__(256, 2) void enc_mfma2_kernel(
    const float* __restrict__ x0, const float* __restrict__ b0,
    const float* __restrict__ x1, const float* __restrict__ b1,
    const ushort* __restrict__ wfrag, float* __restrict__ out, int M)
{
  __shared__ ushort sfrag[16384];                 // 32 KB
  const int enc = blockIdx.y;
  const float* __restrict__ x   = enc ? x1 : x0;
  const float* __restrict__ bia = enc ? b1 : b0;
  float* __restrict__ o = out + (size_t)enc * (size_t)M * 64u;

  const int lane = threadIdx.x & 63;
  const int wid  = threadIdx.x >> 6;
  const int nstrips = (M + 15) >> 4;
  const int gw = blockIdx.x * 4 + wid;
  const int nw = gridDim.x * 4;

  const int rsel = lane & 15;                    // A row / C col within tile
  const int kgrp = lane >> 4;                    // k-group for A, row-group for C
  float bv[4];
#pragma unroll
  for (int nsub = 0; nsub < 4; ++nsub) bv[nsub] = bia[nsub * 16 + rsel];

  // --- prefetch first strip's x before the LDS fill (overlap) ---
  int strip = gw;
  bool active = strip < nstrips;
  f32x4 xa[8], xb[8];
  if (active) {
    int rowL = strip * 16 + rsel; if (rowL >= M) rowL = M - 1;
    const float* xr = x + (size_t)rowL * 256u + kgrp * 8;
#pragma unroll
    for (int ks = 0; ks < 8; ++ks) {
      xa[ks] = *(const f32x4*)(xr + ks * 32);
      xb[ks] = *(const f32x4*)(xr + ks * 32 + 4);
    }
  }

  // --- cooperative LDS fill of this encoder's 32 fragments ---
  {
    const f32x4* src = (const f32x4*)wfrag + (size_t)enc * 2048;
    f32x4* dst = (f32x4*)sfrag;
#pragma unroll
    for (int i = 0; i < 8; ++i)
      dst[threadIdx.x + 256 * i] = src[threadIdx.x + 256 * i];
  }
  __syncthreads();

  while (active) {
    int next = strip + nw;

    // convert current strip to bf16 A-fragments
    bf16x8 a[8];
#pragma unroll
    for (int ks = 0; ks < 8; ++ks) {
      a[ks][0] = f2bf(xa[ks].x); a[ks][1] = f2bf(xa[ks].y);
      a[ks][2] = f2bf(xa[ks].z); a[ks][3] = f2bf(xa[ks].w);
      a[ks][4] = f2bf(xb[ks].x); a[ks][5] = f2bf(xb[ks].y);
      a[ks][6] = f2bf(xb[ks].z); a[ks][7] = f2bf(xb[ks].w);
    }

    // issue next strip's loads — in flight during MFMA + epilogue below
    if (next < nstrips) {
      int rowL = next * 16 + rsel; if (rowL >= M) rowL = M - 1;
      const float* xr = x + (size_t)rowL * 256u + kgrp * 8;
#pragma unroll
      for (int ks = 0; ks < 8; ++ks) {
        xa[ks] = *(const f32x4*)(xr + ks * 32);
        xb[ks] = *(const f32x4*)(xr + ks * 32 + 4);
      }
    }

    // MFMA: B fragments from LDS (contiguous lane*16B -> conflict-free)
    f32x4 acc[4];
#pragma unroll
    for (int nsub = 0; nsub < 4; ++nsub) acc[nsub] = f32x4{0.f, 0.f, 0.f, 0.f};
#pragma unroll
    for (int ks = 0; ks < 8; ++ks) {
#pragma unroll
      for (int nsub = 0; nsub < 4; ++nsub) {
        bf16x8 bfr = *(const bf16x8*)(sfrag + ((size_t)((nsub * 8 + ks) * 64 + lane)) * 8);
        acc[nsub] = __builtin_amdgcn_mfma_f32_16x16x32_bf16(a[ks], bfr, acc[nsub], 0, 0, 0);
      }
    }

    // epilogue: bias + leaky relu; C/D: col=lane&15, row=(lane>>4)*4+r
    int crow = strip * 16 + kgrp * 4;
#pragma unroll
    for (int nsub = 0; nsub < 4; ++nsub) {
#pragma unroll
      for (int r = 0; r < 4; ++r) {
        int rr = crow + r;
        if (rr < M) {
          float v = acc[nsub][r] + bv[nsub];
          v = fmaxf(v, 0.01f * v);
          o[(size_t)rr * 64u + nsub * 16 + rsel] = v;
        }
      }
    }

    strip = next;
    active = next < nstrips;
  }
}

// ---------------------------------------------------------------------------
// Kernel B: pw = xw @ W_edge[0:64,:]  ;  pi = xi @ W_edge[64:128,:]
// ---------------------------------------------------------------------------
__global__ __launch_bounds__(256) void proj_kernel(
    const float* __restrict__ feats, const float* __restrict__ W_edge,
    float* __restrict__ ws, int M)
{
  const int enc = blockIdx.y;
  int row = blockIdx.x * 256 + threadIdx.x;
  if (row >= M) return;
  const float4* __restrict__ f4 =
      (const float4*)(feats + ((size_t)enc * M + row) * 64u);
  const float* __restrict__ W2 = W_edge + enc * 640;   // 64 rows x 10 cols

  float acc[10];
#pragma unroll
  for (int k = 0; k < 10; ++k) acc[k] = 0.f;

#pragma unroll 4
  for (int n4 = 0; n4 < 16; ++n4) {
    float4 xv = f4[n4];
    const float* w = W2 + n4 * 40;
#pragma unroll
    for (int k = 0; k < 10; ++k) acc[k] = fmaf(xv.x, w[k],      acc[k]);
#pragma unroll
    for (int k = 0; k < 10; ++k) acc[k] = fmaf(xv.y, w[10 + k], acc[k]);
#pragma unroll
    for (int k = 0; k < 10; ++k) acc[k] = fmaf(xv.z, w[20 + k], acc[k]);
#pragma unroll
    for (int k = 0; k < 10; ++k) acc[k] = fmaf(xv.w, w[30 + k], acc[k]);
  }

  float* orow = ws + ((size_t)enc * M + row) * 12u;
#pragma unroll
  for (int k = 0; k < 10; ++k) orow[k] = acc[k];
  orow[10] = 0.f; orow[11] = 0.f;
}

// ---------------------------------------------------------------------------
// Kernel C: logits[e] = pw[e0] + pi[e1] + b_edge ; out = log_softmax(logits)
// ---------------------------------------------------------------------------
__global__ __launch_bounds__(256) void edge_kernel(
    const int* __restrict__ ei, const float* __restrict__ ws,
    const float* __restrict__ b_edge, float* __restrict__ out,
    int E, int M)
{
  __shared__ float sm[256 * 11];
  long e = (long)blockIdx.x * 256 + threadIdx.x;
  float l[10];
#pragma unroll
  for (int k = 0; k < 10; ++k) l[k] = 0.f;

  if (e < E) {
    int e0 = ei[e];
    int e1 = ei[E + e];
    const float4* pw = (const float4*)ws + (size_t)e0 * 3u;
    const float4* pi = (const float4*)ws + ((size_t)M + e1) * 3u;
    float4 a0 = pw[0], a1 = pw[1], a2 = pw[2];
    float4 c0 = pi[0], c1 = pi[1], c2 = pi[2];
    l[0] = a0.x + c0.x + b_edge[0];
    l[1] = a0.y + c0.y + b_edge[1];
    l[2] = a0.z + c0.z + b_edge[2];
    l[3] = a0.w + c0.w + b_edge[3];
    l[4] = a1.x + c1.x + b_edge[4];
    l[5] = a1.y + c1.y + b_edge[5];
    l[6] = a1.z + c1.z + b_edge[6];
    l[7] = a1.w + c1.w + b_edge[7];
    l[8] = a2.x + c2.x + b_edge[8];
    l[9] = a2.y + c2.y + b_edge[9];
    float m = l[0];
#pragma unroll
    for (int k = 1; k < 10; ++k) m = fmaxf(m, l[k]);
    float s = 0.f;
#pragma unroll
    for (int k = 0; k < 10; ++k) { l[k] = (l[k] - m) * LOG2E; s += exp2f(l[k]); }
    float ls = log2f(s);
#pragma unroll
    for (int k = 0; k < 10; ++k) l[k] = (l[k] - ls) * LN2;
  }

#pragma unroll
  for (int k = 0; k < 10; ++k) sm[threadIdx.x * 11 + k] = l[k];
  __syncthreads();
  long obase = (long)blockIdx.x * 2560;
  long lim = (long)E * 10;
#pragma unroll
  for (int j = 0; j < 10; ++j) {
    int jj = j * 256 + threadIdx.x;
    long oi = obase + jj;
    if (oi < lim) out[oi] = sm[(jj / 10) * 11 + (jj % 10)];
  }
}

// ---------------------------------------------------------------------------
// Fallback f32 encoder + direct edge (only if d_ws too small).
// ---------------------------------------------------------------------------
__global__ __launch_bounds__(256) void enc_kernel_f32(
    const float* __restrict__ x0, const float* __restrict__ W0, const float* __restrict__ b0,
    const float* __restrict__ x1, const float* __restrict__ W1, const float* __restrict__ b1,
    float* __restrict__ out, int M)
{
  const int enc = blockIdx.y;
  const float* __restrict__ x = enc ? x1 : x0;
  const float* __restrict__ W = enc ? W1 : W0;
  const float* __restrict__ b = enc ? b1 : b0;
  float* __restrict__ o = out + (size_t)enc * (size_t)M * 64u;

  const int lane = threadIdx.x & 63;
  const int wid  = threadIdx.x >> 6;
  int row0 = __builtin_amdgcn_readfirstlane(blockIdx.x * 64 + wid * 16);
  const float* __restrict__ xrow = x + (size_t)row0 * 256u;

  float acc[16];
#pragma unroll
  for (int r = 0; r < 16; ++r) acc[r] = 0.f;

  if (row0 + 16 <= M) {
#pragma unroll 4
    for (int k = 0; k < 256; ++k) {
      float wv = W[k * 64 + lane];
#pragma unroll
      for (int r = 0; r < 16; ++r)
        acc[r] = fmaf(xrow[r * 256 + k], wv, acc[r]);
    }
    float bias = b[lane];
#pragma unroll
    for (int r = 0; r < 16; ++r) {
      float v = acc[r] + bias;
      v = fmaxf(v, 0.01f * v);
      o[(size_t)(row0 + r) * 64u + lane] = v;
    }
  } else if (row0 < M) {
    int nr = M - row0;
    for (int k = 0; k < 256; ++k) {
      float wv = W[k * 64 + lane];
      for (int r = 0; r < nr; ++r)
        acc[r] = fmaf(xrow[r * 256 + k], wv, acc[r]);
    }
    float bias = b[lane];
    for (int r = 0; r < nr; ++r) {
      float v = acc[r] + bias;
      v = fmaxf(v, 0.01f * v);
      o[(size_t)(row0 + r) * 64u + lane] = v;
    }
  }
}

__global__ __launch_bounds__(256) void edge_kernel_direct(
    const int* __restrict__ ei, const float* __restrict__ feats,
    const float* __restrict__ W_edge, const float* __restrict__ b_edge,
    float* __restrict__ out, int E, int M)
{
  __shared__ float sm[256 * 11];
  long e = (long)blockIdx.x * 256 + threadIdx.x;
  float l[10];
#pragma unroll
  for (int k = 0; k < 10; ++k) l[k] = 0.f;

  if (e < E) {
    int e0 = ei[e];
    int e1 = ei[E + e];
#pragma unroll
    for (int k = 0; k < 10; ++k) l[k] = b_edge[k];
    const float4* fw = (const float4*)(feats + (size_t)e0 * 64u);
    const float4* fi = (const float4*)(feats + ((size_t)M + e1) * 64u);
#pragma unroll 4
    for (int n4 = 0; n4 < 16; ++n4) {
      float4 xv = fw[n4];
      const float* w = W_edge + n4 * 40;
#pragma unroll
      for (int k = 0; k < 10; ++k) l[k] = fmaf(xv.x, w[k],      l[k]);
#pragma unroll
      for (int k = 0; k < 10; ++k) l[k] = fmaf(xv.y, w[10 + k], l[k]);
#pragma unroll
      for (int k = 0; k < 10; ++k) l[k] = fmaf(xv.z, w[20 + k], l[k]);
#pragma unroll
      for (int k = 0; k < 10; ++k) l[k] = fmaf(xv.w, w[30 + k], l[k]);
    }
#pragma unroll 4
    for (int n4 = 0; n4 < 16; ++n4) {
      float4 xv = fi[n4];
      const float* w = W_edge + 640 + n4 * 40;
#pragma unroll
      for (int k = 0; k < 10; ++k) l[k] = fmaf(xv.x, w[k],      l[k]);
#pragma unroll
      for (int k = 0; k < 10; ++k) l[k] = fmaf(xv.y, w[10 + k], l[k]);
#pragma unroll
      for (int k = 0; k < 10; ++k) l[k] = fmaf(xv.z, w[20 + k], l[k]);
#pragma unroll
      for (int k = 0; k < 10; ++k) l[k] = fmaf(xv.w, w[30 + k], l[k]);
    }
    float m = l[0];
#pragma unroll
    for (int k = 1; k < 10; ++k) m = fmaxf(m, l[k]);
    float s = 0.f;
#pragma unroll
    for (int k = 0; k < 10; ++k) { l[k] = (l[k] - m) * LOG2E; s += exp2f(l[k]); }
    float ls = log2f(s);
#pragma unroll
    for (int k = 0; k < 10; ++k) l[k] = (l[k] - ls) * LN2;
  }

#pragma unroll
  for (int k = 0; k < 10; ++k) sm[threadIdx.x * 11 + k] = l[k];
  __syncthreads();
  long obase = (long)blockIdx.x * 2560;
  long lim = (long)E * 10;
#pragma unroll
  for (int j = 0; j < 10; ++j) {
    int jj = j * 256 + threadIdx.x;
    long oi = obase + jj;
    if (oi < lim) out[oi] = sm[(jj / 10) * 11 + (jj % 10)];
  }
}

extern "C" void kernel_launch(void* const* d_in, const int* in_sizes, int n_in,
                              void* d_out, int out_size, void* d_ws, size_t ws_size,
                              hipStream_t stream)
{
  const float* x_w = (const float*)d_in[0];
  const float* x_i = (const float*)d_in[1];
  const int*   ei  = (const int*)d_in[2];
  const float* W_w = (const float*)d_in[3];
  const float* b_w = (const float*)d_in[4];
  const float* W_i = (const float*)d_in[5];
  const float* b_i = (const float*)d_in[6];
  const float* W_e = (const float*)d_in[7];
  const float* b_e = (const float*)d_in[8];
  float* out = (float*)d_out;

  const int M = in_sizes[0] / 256;   // 100000
  const int E = in_sizes[2] / 2;     // 2000000

  float* logout = out + (size_t)2 * (size_t)M * 64u;

  const size_t pw_bytes = (size_t)2 * (size_t)M * 12u * sizeof(float);
  const size_t ws_need  = pw_bytes + 65536;     // + wfrag table

  if (ws_size >= ws_need) {
    float*  ws    = (float*)d_ws;
    ushort* wfrag = (ushort*)((char*)d_ws + pw_bytes);

    wprep_kernel<<<16, 256, 0, stream>>>(W_w, W_i, wfrag);

    dim3 gA(256, 2);                 // grid-stride: ~6 strips per wave
    enc_mfma2_kernel<<<gA, 256, 0, stream>>>(x_w, b_w, x_i, b_i, wfrag, out, M);

    dim3 gB((M + 255) / 256, 2);
    proj_kernel<<<gB, 256, 0, stream>>>(out, W_e, ws, M);

    dim3 gC((unsigned)((E + 255) / 256));
    edge_kernel<<<gC, 256, 0, stream>>>(ei, ws, b_e, logout, E, M);
  } else {
    dim3 gA0((M + 63) / 64, 2);
    enc_kernel_f32<<<gA0, 256, 0, stream>>>(x_w, W_w, b_w, x_i, W_i, b_i, out, M);
    dim3 gC((unsigned)((E + 255) / 256));
    edge_kernel_direct<<<gC, 256, 0, stream>>>(ei, out, W_e, b_e, logout, E, M);
  }
}

// Round 4
// 141.774 us; speedup vs baseline: 3.4068x; 1.1008x over previous
//
#include <hip/hip_runtime.h>
#include <hip/hip_bf16.h>

#define LOG2E 1.4426950408889634f
#define LN2   0.6931471805599453f

typedef __attribute__((ext_vector_type(8))) short bf16x8;
typedef __attribute__((ext_vector_type(4))) float f32x4;

static __device__ __forceinline__ short f2bf(float f) {
  __hip_bfloat16 h = __float2bfloat16(f);
  return *reinterpret_cast<short*>(&h);
}

static __device__ __forceinline__ void gll16(const float* gsrc, float* ldst) {
  // 16B per lane: global per-lane src, wave-uniform LDS base + lane*16
  __builtin_amdgcn_global_load_lds(
      (const __attribute__((address_space(1))) void*)gsrc,
      (__attribute__((address_space(3))) void*)ldst, 16, 0, 0);
}

// ---------------------------------------------------------------------------
// wprep: pack W_worker/W_item (f32 [256][64]) into per-lane MFMA B-fragments.
// wfrag[enc][f][lane][j], f = nsub*8+ks; elem = W[ks*32+(lane>>4)*8+j][nsub*16+(lane&15)]
// ---------------------------------------------------------------------------
__global__ __launch_bounds__(256) void wprep_kernel(
    const float* __restrict__ Ww, const float* __restrict__ Wi,
    ushort* __restrict__ wfrag)
{
  int id = blockIdx.x * 256 + threadIdx.x;       // 0..4095
  if (id >= 4096) return;
  int enc  = id >> 11;
  int f    = (id >> 6) & 31;
  int l    = id & 63;
  int nsub = f >> 3, ks = f & 7;
  const float* __restrict__ W = enc ? Wi : Ww;
  int n  = nsub * 16 + (l & 15);
  int k0 = ks * 32 + (l >> 4) * 8;
  ushort* dst = wfrag + ((size_t)(enc * 32 + f) * 64 + l) * 8;
#pragma unroll
  for (int j = 0; j < 8; ++j)
    dst[j] = (ushort)f2bf(W[(size_t)(k0 + j) * 64 + n]);
}

// ---------------------------------------------------------------------------
// enc_mfma3: x staged per-wave in LDS via global_load_lds (dense 1KB/instr,
// source-side XOR swizzle) -> ds_read_b128 fragments -> bf16 MFMA.
// LDS: 32KB W frags + 4 waves x 16KB x-buffers = 96KB -> 1 block/CU.
// ---------------------------------------------------------------------------
__global__ __launch_bounds__(256, 1) void enc_mfma3_kernel(
    const float* __restrict__ x0, const float* __restrict__ b0,
    const float* __restrict__ x1, const float* __restrict__ b1,
    const ushort* __restrict__ wfrag, float* __restrict__ out, int M)
{
  __shared__ ushort sfrag[16384];                 // 32 KB W fragments
  __shared__ float  xstg[4][4096];                // 4 waves x 16 KB

  const int enc = blockIdx.y;
  const float* __restrict__ x   = enc ? x1 : x0;
  const float* __restrict__ bia = enc ? b1 : b0;
  float* __restrict__ o = out + (size_t)enc * (size_t)M * 64u;

  const int lane = threadIdx.x & 63;
  const int wid  = threadIdx.x >> 6;
  const int rsel = lane & 15;                     // A row / C col within tile
  const int kgrp = lane >> 4;                     // k-group / C row-group
  const int swz  = rsel & 7;

  const int nstrips = (M + 15) >> 4;
  int strip = blockIdx.x * 4 + wid;
  const int nw = gridDim.x * 4;

  float bv[4];
#pragma unroll
  for (int nsub = 0; nsub < 4; ++nsub) bv[nsub] = bia[nsub * 16 + rsel];

  // cooperative LDS fill of W fragments
  {
    const f32x4* src = (const f32x4*)wfrag + (size_t)enc * 2048;
    f32x4* dst = (f32x4*)sfrag;
#pragma unroll
    for (int i = 0; i < 8; ++i)
      dst[threadIdx.x + 256 * i] = src[threadIdx.x + 256 * i];
  }
  __syncthreads();

  float* xw = xstg[wid];
  bool active = strip < nstrips;

  // prologue: stage strip's 16 rows (one dense 1KB gll per row, swizzled src)
  if (active) {
#pragma unroll
    for (int r = 0; r < 16; ++r) {
      int rg = strip * 16 + r; if (rg >= M) rg = M - 1;
      const float* gs = x + (size_t)rg * 256u + ((lane ^ (r & 7)) << 2);
      gll16(gs, xw + r * 256);
    }
  }

  while (active) {
    int next = strip + nw;

    asm volatile("s_waitcnt vmcnt(0)" ::: "memory");   // buffer ready
    __builtin_amdgcn_sched_barrier(0);

    // read A-fragments (swizzled) and convert to bf16
    bf16x8 a[8];
#pragma unroll
    for (int ks = 0; ks < 8; ++ks) {
      int c0 = kgrp * 2 + ks * 8;
      f32x4 lo = *(const f32x4*)&xw[rsel * 256 + (((c0    ) ^ swz) << 2)];
      f32x4 hi = *(const f32x4*)&xw[rsel * 256 + (((c0 + 1) ^ swz) << 2)];
      a[ks][0] = f2bf(lo.x); a[ks][1] = f2bf(lo.y);
      a[ks][2] = f2bf(lo.z); a[ks][3] = f2bf(lo.w);
      a[ks][4] = f2bf(hi.x); a[ks][5] = f2bf(hi.y);
      a[ks][6] = f2bf(hi.z); a[ks][7] = f2bf(hi.w);
    }

    asm volatile("s_waitcnt lgkmcnt(0)" ::: "memory"); // buffer fully consumed
    __builtin_amdgcn_sched_barrier(0);

    // refill: issue next strip's loads (in flight under MFMA + epilogue)
    if (next < nstrips) {
#pragma unroll
      for (int r = 0; r < 16; ++r) {
        int rg = next * 16 + r; if (rg >= M) rg = M - 1;
        const float* gs = x + (size_t)rg * 256u + ((lane ^ (r & 7)) << 2);
        gll16(gs, xw + r * 256);
      }
    }

    // MFMA: B fragments from LDS (lane-dense, conflict-free)
    f32x4 acc[4];
#pragma unroll
    for (int nsub = 0; nsub < 4; ++nsub) acc[nsub] = f32x4{0.f, 0.f, 0.f, 0.f};
#pragma unroll
    for (int ks = 0; ks < 8; ++ks) {
#pragma unroll
      for (int nsub = 0; nsub < 4; ++nsub) {
        bf16x8 bfr = *(const bf16x8*)(sfrag + ((size_t)((nsub * 8 + ks) * 64 + lane)) * 8);
        acc[nsub] = __builtin_amdgcn_mfma_f32_16x16x32_bf16(a[ks], bfr, acc[nsub], 0, 0, 0);
      }
    }

    // epilogue: bias + leaky relu; C/D: col=lane&15, row=(lane>>4)*4+r
    int crow = strip * 16 + kgrp * 4;
#pragma unroll
    for (int nsub = 0; nsub < 4; ++nsub) {
#pragma unroll
      for (int r = 0; r < 4; ++r) {
        int rr = crow + r;
        if (rr < M) {
          float v = acc[nsub][r] + bv[nsub];
          v = fmaxf(v, 0.01f * v);
          o[(size_t)rr * 64u + nsub * 16 + rsel] = v;
        }
      }
    }

    strip = next;
    active = next < nstrips;
  }
}

// ---------------------------------------------------------------------------
// Kernel B: pw = xw @ W_edge[0:64,:] ; pi = xi @ W_edge[64:128,:]
// rows padded to 16 floats (64B) -> every edge gather is a single 128B line.
// ---------------------------------------------------------------------------
__global__ __launch_bounds__(256) void proj_kernel(
    const float* __restrict__ feats, const float* __restrict__ W_edge,
    float* __restrict__ ws, int M)
{
  const int enc = blockIdx.y;
  int row = blockIdx.x * 256 + threadIdx.x;
  if (row >= M) return;
  const float4* __restrict__ f4 =
      (const float4*)(feats + ((size_t)enc * M + row) * 64u);
  const float* __restrict__ W2 = W_edge + enc * 640;   // 64 rows x 10 cols

  float acc[10];
#pragma unroll
  for (int k = 0; k < 10; ++k) acc[k] = 0.f;

#pragma unroll 4
  for (int n4 = 0; n4 < 16; ++n4) {
    float4 xv = f4[n4];
    const float* w = W2 + n4 * 40;
#pragma unroll
    for (int k = 0; k < 10; ++k) acc[k] = fmaf(xv.x, w[k],      acc[k]);
#pragma unroll
    for (int k = 0; k < 10; ++k) acc[k] = fmaf(xv.y, w[10 + k], acc[k]);
#pragma unroll
    for (int k = 0; k < 10; ++k) acc[k] = fmaf(xv.z, w[20 + k], acc[k]);
#pragma unroll
    for (int k = 0; k < 10; ++k) acc[k] = fmaf(xv.w, w[30 + k], acc[k]);
  }

  float* orow = ws + ((size_t)enc * M + row) * 16u;
#pragma unroll
  for (int k = 0; k < 10; ++k) orow[k] = acc[k];
  orow[10] = 0.f; orow[11] = 0.f;
}

// ---------------------------------------------------------------------------
// Kernel C: logits[e] = pw[e0] + pi[e1] + b_edge ; out = log_softmax(logits)
// ---------------------------------------------------------------------------
__global__ __launch_bounds__(256) void edge_kernel(
    const int* __restrict__ ei, const float* __restrict__ ws,
    const float* __restrict__ b_edge, float* __restrict__ out,
    int E, int M)
{
  __shared__ float sm[256 * 11];
  long e = (long)blockIdx.x * 256 + threadIdx.x;
  float l[10];
#pragma unroll
  for (int k = 0; k < 10; ++k) l[k] = 0.f;

  if (e < E) {
    int e0 = ei[e];
    int e1 = ei[E + e];
    const float4* pw = (const float4*)ws + (size_t)e0 * 4u;
    const float4* pi = (const float4*)ws + ((size_t)M + e1) * 4u;
    float4 a0 = pw[0], a1 = pw[1], a2 = pw[2];
    float4 c0 = pi[0], c1 = pi[1], c2 = pi[2];
    l[0] = a0.x + c0.x + b_edge[0];
    l[1] = a0.y + c0.y + b_edge[1];
    l[2] = a0.z + c0.z + b_edge[2];
    l[3] = a0.w + c0.w + b_edge[3];
    l[4] = a1.x + c1.x + b_edge[4];
    l[5] = a1.y + c1.y + b_edge[5];
    l[6] = a1.z + c1.z + b_edge[6];
    l[7] = a1.w + c1.w + b_edge[7];
    l[8] = a2.x + c2.x + b_edge[8];
    l[9] = a2.y + c2.y + b_edge[9];
    float m = l[0];
#pragma unroll
    for (int k = 1; k < 10; ++k) m = fmaxf(m, l[k]);
    float s = 0.f;
#pragma unroll
    for (int k = 0; k < 10; ++k) { l[k] = (l[k] - m) * LOG2E; s += exp2f(l[k]); }
    float ls = log2f(s);
#pragma unroll
    for (int k = 0; k < 10; ++k) l[k] = (l[k] - ls) * LN2;
  }

#pragma unroll
  for (int k = 0; k < 10; ++k) sm[threadIdx.x * 11 + k] = l[k];
  __syncthreads();
  long obase = (long)blockIdx.x * 2560;
  long lim = (long)E * 10;
#pragma unroll
  for (int j = 0; j < 10; ++j) {
    int jj = j * 256 + threadIdx.x;
    long oi = obase + jj;
    if (oi < lim) out[oi] = sm[(jj / 10) * 11 + (jj % 10)];
  }
}

// ---------------------------------------------------------------------------
// Fallbacks (only if d_ws too small).
// ---------------------------------------------------------------------------
__global__ __launch_bounds__(256) void enc_kernel_f32(
    const float* __restrict__ x0, const float* __restrict__ W0, const float* __restrict__ b0,
    const float* __restrict__ x1, const float* __restrict__ W1, const float* __restrict__ b1,
    float* __restrict__ out, int M)
{
  const int enc = blockIdx.y;
  const float* __restrict__ x = enc ? x1 : x0;
  const float* __restrict__ W = enc ? W1 : W0;
  const float* __restrict__ b = enc ? b1 : b0;
  float* __restrict__ o = out + (size_t)enc * (size_t)M * 64u;

  const int lane = threadIdx.x & 63;
  const int wid  = threadIdx.x >> 6;
  int row0 = __builtin_amdgcn_readfirstlane(blockIdx.x * 64 + wid * 16);
  const float* __restrict__ xrow = x + (size_t)row0 * 256u;

  float acc[16];
#pragma unroll
  for (int r = 0; r < 16; ++r) acc[r] = 0.f;

  if (row0 + 16 <= M) {
#pragma unroll 4
    for (int k = 0; k < 256; ++k) {
      float wv = W[k * 64 + lane];
#pragma unroll
      for (int r = 0; r < 16; ++r)
        acc[r] = fmaf(xrow[r * 256 + k], wv, acc[r]);
    }
    float bias = b[lane];
#pragma unroll
    for (int r = 0; r < 16; ++r) {
      float v = acc[r] + bias;
      v = fmaxf(v, 0.01f * v);
      o[(size_t)(row0 + r) * 64u + lane] = v;
    }
  } else if (row0 < M) {
    int nr = M - row0;
    for (int k = 0; k < 256; ++k) {
      float wv = W[k * 64 + lane];
      for (int r = 0; r < nr; ++r)
        acc[r] = fmaf(xrow[r * 256 + k], wv, acc[r]);
    }
    float bias = b[lane];
    for (int r = 0; r < nr; ++r) {
      float v = acc[r] + bias;
      v = fmaxf(v, 0.01f * v);
      o[(size_t)(row0 + r) * 64u + lane] = v;
    }
  }
}

__global__ __launch_bounds__(256) void edge_kernel_direct(
    const int* __restrict__ ei, const float* __restrict__ feats,
    const float* __restrict__ W_edge, const float* __restrict__ b_edge,
    float* __restrict__ out, int E, int M)
{
  __shared__ float sm[256 * 11];
  long e = (long)blockIdx.x * 256 + threadIdx.x;
  float l[10];
#pragma unroll
  for (int k = 0; k < 10; ++k) l[k] = 0.f;

  if (e < E) {
    int e0 = ei[e];
    int e1 = ei[E + e];
#pragma unroll
    for (int k = 0; k < 10; ++k) l[k] = b_edge[k];
    const float4* fw = (const float4*)(feats + (size_t)e0 * 64u);
    const float4* fi = (const float4*)(feats + ((size_t)M + e1) * 64u);
#pragma unroll 4
    for (int n4 = 0; n4 < 16; ++n4) {
      float4 xv = fw[n4];
      const float* w = W_edge + n4 * 40;
#pragma unroll
      for (int k = 0; k < 10; ++k) l[k] = fmaf(xv.x, w[k],      l[k]);
#pragma unroll
      for (int k = 0; k < 10; ++k) l[k] = fmaf(xv.y, w[10 + k], l[k]);
#pragma unroll
      for (int k = 0; k < 10; ++k) l[k] = fmaf(xv.z, w[20 + k], l[k]);
#pragma unroll
      for (int k = 0; k < 10; ++k) l[k] = fmaf(xv.w, w[30 + k], l[k]);
    }
#pragma unroll 4
    for (int n4 = 0; n4 < 16; ++n4) {
      float4 xv = fi[n4];
      const float* w = W_edge + 640 + n4 * 40;
#pragma unroll
      for (int k = 0; k < 10; ++k) l[k] = fmaf(xv.x, w[k],      l[k]);
#pragma unroll
      for (int k = 0; k < 10; ++k) l[k] = fmaf(xv.y, w[10 + k], l[k]);
#pragma unroll
      for (int k = 0; k < 10; ++k) l[k] = fmaf(xv.z, w[20 + k], l[k]);
#pragma unroll
      for (int k = 0; k < 10; ++k) l[k] = fmaf(xv.w, w[30 + k], l[k]);
    }
    float m = l[0];
#pragma unroll
    for (int k = 1; k < 10; ++k) m = fmaxf(m, l[k]);
    float s = 0.f;
#pragma unroll
    for (int k = 0; k < 10; ++k) { l[k] = (l[k] - m) * LOG2E; s += exp2f(l[k]); }
    float ls = log2f(s);
#pragma unroll
    for (int k = 0; k < 10; ++k) l[k] = (l[k] - ls) * LN2;
  }

#pragma unroll
  for (int k = 0; k < 10; ++k) sm[threadIdx.x * 11 + k] = l[k];
  __syncthreads();
  long obase = (long)blockIdx.x * 2560;
  long lim = (long)E * 10;
#pragma unroll
  for (int j = 0; j < 10; ++j) {
    int jj = j * 256 + threadIdx.x;
    long oi = obase + jj;
    if (oi < lim) out[oi] = sm[(jj / 10) * 11 + (jj % 10)];
  }
}

extern "C" void kernel_launch(void* const* d_in, const int* in_sizes, int n_in,
                              void* d_out, int out_size, void* d_ws, size_t ws_size,
                              hipStream_t stream)
{
  const float* x_w = (const float*)d_in[0];
  const float* x_i = (const float*)d_in[1];
  const int*   ei  = (const int*)d_in[2];
  const float* W_w = (const float*)d_in[3];
  const float* b_w = (const float*)d_in[4];
  const float* W_i = (const float*)d_in[5];
  const float* b_i = (const float*)d_in[6];
  const float* W_e = (const float*)d_in[7];
  const float* b_e = (const float*)d_in[8];
  float* out = (float*)d_out;

  const int M = in_sizes[0] / 256;   // 100000
  const int E = in_sizes[2] / 2;     // 2000000

  float* logout = out + (size_t)2 * (size_t)M * 64u;

  const size_t pw_bytes = (size_t)2 * (size_t)M * 16u * sizeof(float);
  const size_t ws_need  = pw_bytes + 65536;     // + wfrag table

  if (ws_size >= ws_need) {
    float*  ws    = (float*)d_ws;
    ushort* wfrag = (ushort*)((char*)d_ws + pw_bytes);

    wprep_kernel<<<16, 256, 0, stream>>>(W_w, W_i, wfrag);

    dim3 gA(128, 2);                 // 256 blocks -> 1/CU; grid-stride strips
    enc_mfma3_kernel<<<gA, 256, 0, stream>>>(x_w, b_w, x_i, b_i, wfrag, out, M);

    dim3 gB((M + 255) / 256, 2);
    proj_kernel<<<gB, 256, 0, stream>>>(out, W_e, ws, M);

    dim3 gC((unsigned)((E + 255) / 256));
    edge_kernel<<<gC, 256, 0, stream>>>(ei, ws, b_e, logout, E, M);
  } else {
    dim3 gA0((M + 63) / 64, 2);
    enc_kernel_f32<<<gA0, 256, 0, stream>>>(x_w, W_w, b_w, x_i, W_i, b_i, out, M);
    dim3 gC((unsigned)((E + 255) / 256));
    edge_kernel_direct<<<gC, 256, 0, stream>>>(ei, out, W_e, b_e, logout, E, M);
  }
}